// Round 1
// baseline (238.132 us; speedup 1.0000x reference)
//
#include <hip/hip_runtime.h>

#define NB 64
#define NN 100
#define DL 32
#define BN (NB * NN)  // 6400

typedef _Float16 f16x8 __attribute__((ext_vector_type(8)));
typedef float f32x4 __attribute__((ext_vector_type(4)));

static __device__ __forceinline__ float lrelu(float x) { return fmaxf(x, 0.1f * x); }
static __device__ __forceinline__ f32x4 lrelu4(f32x4 x) {
    return __builtin_elementwise_max(x, 0.1f * x);
}
static __device__ __forceinline__ f32x4 ld4(const float* p) { return *(const f32x4*)p; }
static __device__ __forceinline__ float hsum4(f32x4 v) { return v[0] + v[1] + v[2] + v[3]; }

// Fused pre-pass:
//  blocks 0..1599   : h = x@lin_w+lin_b (4 rows each), U/V for step 0
//  blocks 1600..1601: PW f16 B-fragment swizzle (edge W1, both steps)
//  blocks 1602..1603: transpose node W0 (96x64 -> [64][96]) per step
//  blocks 1604..1605: transpose node W1 (64x32 -> [32][64]) per step
//  block  1606      : TUV  = transposed U/V weights of step-1 edge W0 ([128][32])
//  block  1607      : OWT  = transposed out weights ([3][32])
__global__ __launch_bounds__(256) void k_pre(
    const float* __restrict__ x, const float* __restrict__ lw, const float* __restrict__ lb,
    const float* __restrict__ ew0a, const float* __restrict__ eb0a,
    const float* __restrict__ w1a, const float* __restrict__ w1b,
    const float* __restrict__ nw0a, const float* __restrict__ nw0b,
    const float* __restrict__ nw1a, const float* __restrict__ nw1b,
    const float* __restrict__ ew0b, const float* __restrict__ ow,
    float* __restrict__ h, float* __restrict__ U, float* __restrict__ V,
    _Float16* __restrict__ PW,
    float* __restrict__ tw0n, float* __restrict__ tw1n,
    float* __restrict__ tuv, float* __restrict__ owt) {
    int blk = blockIdx.x;
    int t = threadIdx.x;
    if (blk >= 1600) {
        if (blk < 1602) {  // PW[step][kt][hf][lane][jj]
            int step = blk - 1600;
            const float* w1 = step ? w1b : w1a;
            _Float16* dst = PW + step * 4096;
#pragma unroll
            for (int u = 0; u < 16; ++u) {
                int idx = t * 16 + u;
                int jj = idx & 7, lane = (idx >> 3) & 63, hf = (idx >> 9) & 1, kt = idx >> 10;
                int c = hf * 32 + (lane >> 4) * 8 + jj;
                int k = kt * 16 + (lane & 15);
                dst[idx] = (_Float16)w1[c * 64 + k];
            }
        } else if (blk < 1604) {  // node W0 transpose: [64 k][96 c]
            int s = blk - 1602;
            const float* src = s ? nw0b : nw0a;
            float* dst = tw0n + s * 6144;
            for (int u = t; u < 6144; u += 256) {
                int k = u / 96, c = u - k * 96;
                dst[u] = src[c * 64 + k];
            }
        } else if (blk < 1606) {  // node W1 transpose: [32 k][64 c]
            int s = blk - 1604;
            const float* src = s ? nw1b : nw1a;
            float* dst = tw1n + s * 2048;
            for (int u = t; u < 2048; u += 256) {
                int k = u >> 6, c = u & 63;
                dst[u] = src[c * 32 + k];
            }
        } else if (blk == 1606) {  // TUV [128][32]: rows 0..63 = U cols, 64..127 = V cols
            for (int u = t; u < 4096; u += 256) {
                int r = u >> 5, c = u & 31;
                int k = r & 63, half = r >> 6;
                tuv[u] = ew0b[(half * 32 + c) * 64 + k];
            }
        } else {  // OWT [3][32]
            if (t < 96) {
                int k = t >> 5, c = t & 31;
                owt[t] = ow[c * 3 + k];
            }
        }
        return;
    }
    __shared__ float xs[DL];
    __shared__ float hs[4][DL];
    int row0 = blk * 4;
    int b = row0 / NN;  // 4-row group never crosses a batch boundary (100 % 4 == 0)
    if (t < DL) xs[t] = x[b * DL + t];
    __syncthreads();
    if (t < 128) {
        int ni = t >> 5, c = t & 31;
        int n = (row0 + ni) % NN;
        float s = lb[n * DL + c];
#pragma unroll
        for (int cc = 0; cc < DL; ++cc) s += xs[cc] * lw[cc * 3200 + n * DL + c];
        hs[ni][c] = s;
        h[(row0 + ni) * DL + c] = s;
    }
    __syncthreads();
#pragma unroll
    for (int r = 0; r < 2; ++r) {
        int o = r * 256 + t;  // 0..511 : 4 rows x (64 U + 64 V)
        int ni = o >> 7, kw = o & 127;
        int which = kw >> 6, k = kw & 63;
        const float* wp = ew0a + (which ? DL * 64 : 0) + k;
        float s = which ? 0.f : eb0a[k];
#pragma unroll
        for (int c = 0; c < DL; ++c) s += hs[ni][c] * wp[c * 64];
        (which ? V : U)[(row0 + ni) * 64 + k] = s;
    }
}

// Per-wave-independent edge+node step. Block = 4 waves = 4 (b,i) rows; ONE barrier
// total (PW staging). Each lane builds its exact MFMA A-fragment in registers:
// lane (q,kk) owns P[row kk][cols q*8..+7, 32+q*8..+7] of each 16-row j-tile.
// Wave does all 4 k-tiles (8 MFMAs/tile) itself; agg reduced with 2 shfl_xor.
// Node MLP / U-V / out done per-wave with pre-transposed weight rows.
template <int FINAL>
__global__ __launch_bounds__(256) void k_edge(
    const float* __restrict__ h, const float* __restrict__ U, const float* __restrict__ V,
    const float* __restrict__ w0, const _Float16* __restrict__ PW,
    const float* __restrict__ b1,
    const float* __restrict__ tw0n, const float* __restrict__ b0n,
    const float* __restrict__ tw1n, const float* __restrict__ b1n,
    const float* __restrict__ wA, const float* __restrict__ bA,
    float* __restrict__ hout, float* __restrict__ Uo, float* __restrict__ Vo,
    float* __restrict__ out) {
    __shared__ __align__(16) _Float16 pwl[4096];
    __shared__ float sdist[4][112];
    __shared__ __align__(16) float sxin[4][96];  // [0..31]=h_i, [32..95]=agg
    __shared__ __align__(16) float st0[4][64];
    __shared__ __align__(16) float sh2[4][32];

    int t = threadIdx.x;
    {  // stage W1 B-fragments once for the whole block
        const f16x8* srcp = (const f16x8*)PW;
        f16x8* dstp = (f16x8*)pwl;
        dstp[t] = srcp[t];
        dstp[t + 256] = srcp[t + 256];
    }
    int w = t >> 6, lane = t & 63, q = lane >> 4, kk = lane & 15;
    int bi = blockIdx.x * 4 + w;
    int b = bi / NN;

    // h_i -> LDS (wave-local, in-order, no barrier needed)
    if (lane < 32) sxin[w][lane] = h[bi * DL + lane];
    // distances for all j (pad 100..111 clamped to j=99; those rows masked later)
    const float* hb = h + b * NN * DL;
    for (int jj = lane; jj < 112; jj += 64) {
        int jc = jj < NN ? jj : NN - 1;
        const float* hj = hb + jc * DL;
        f32x4 s4 = {0.f, 0.f, 0.f, 0.f};
#pragma unroll
        for (int c4 = 0; c4 < 8; ++c4) {
            f32x4 hi4 = ld4(&sxin[w][c4 * 4]);
            f32x4 hj4 = ld4(&hj[c4 * 4]);
            f32x4 d = hi4 - hj4;
            s4 += d * d;
        }
        sdist[w][jj] = sqrtf(hsum4(s4) + 1e-12f);
    }

    int c0 = q * 8;  // this lane's channel base
    const float* Up = U + (size_t)bi * 64;
    f32x4 u0 = ld4(Up + c0), u1 = ld4(Up + c0 + 4);
    f32x4 u2 = ld4(Up + 32 + c0), u3 = ld4(Up + 36 + c0);
    const float* wd = w0 + 64 * 64;  // dist row of edge W0
    f32x4 d0 = ld4(wd + c0), d1 = ld4(wd + c0 + 4);
    f32x4 d2 = ld4(wd + 32 + c0), d3 = ld4(wd + 36 + c0);
    float b1k[4];
#pragma unroll
    for (int kt = 0; kt < 4; ++kt) b1k[kt] = b1[kt * 16 + kk];
    float m6 = (q == 0) ? 1.f : 0.f;  // tile 6: only rows 96..99 (q==0) are valid

    __syncthreads();  // pwl ready

    f32x4 sacc[4];
    f32x4 zero4 = {0.f, 0.f, 0.f, 0.f};
#pragma unroll
    for (int kt = 0; kt < 4; ++kt) sacc[kt] = zero4;
    const float* Vb = V + (size_t)b * NN * 64;

    // prefetch tile 0 (j = kk < 100, no clamp)
    f32x4 v0, v1, v2, v3;
    float dj;
    {
        const float* vr = Vb + kk * 64 + c0;
        v0 = ld4(vr); v1 = ld4(vr + 4); v2 = ld4(vr + 32); v3 = ld4(vr + 36);
        dj = sdist[w][kk];
    }

#pragma unroll
    for (int jt = 0; jt < 7; ++jt) {
        f32x4 cv0 = v0, cv1 = v1, cv2 = v2, cv3 = v3;
        float cdj = dj;
        if (jt < 6) {  // prefetch next tile's V row + dist (hidden behind MFMAs)
            int j = (jt + 1) * 16 + kk;
            int jc = (jt == 5 && j >= NN) ? NN - 1 : j;
            const float* vr = Vb + jc * 64 + c0;
            v0 = ld4(vr); v1 = ld4(vr + 4); v2 = ld4(vr + 32); v3 = ld4(vr + 36);
            dj = sdist[w][j];
        }
        // P build: exactly this lane's A-fragment elements
        f32x4 p0 = lrelu4(u0 + cv0 + cdj * d0);
        f32x4 p1 = lrelu4(u1 + cv1 + cdj * d1);
        f32x4 p2 = lrelu4(u2 + cv2 + cdj * d2);
        f32x4 p3 = lrelu4(u3 + cv3 + cdj * d3);
        f16x8 A0, A1;
        A0[0] = (_Float16)p0[0]; A0[1] = (_Float16)p0[1];
        A0[2] = (_Float16)p0[2]; A0[3] = (_Float16)p0[3];
        A0[4] = (_Float16)p1[0]; A0[5] = (_Float16)p1[1];
        A0[6] = (_Float16)p1[2]; A0[7] = (_Float16)p1[3];
        A1[0] = (_Float16)p2[0]; A1[1] = (_Float16)p2[1];
        A1[2] = (_Float16)p2[2]; A1[3] = (_Float16)p2[3];
        A1[4] = (_Float16)p3[0]; A1[5] = (_Float16)p3[1];
        A1[6] = (_Float16)p3[2]; A1[7] = (_Float16)p3[3];
#pragma unroll
        for (int kt = 0; kt < 4; ++kt) {
            f16x8 B0 = *(const f16x8*)&pwl[(kt * 2 + 0) * 512 + lane * 8];
            f16x8 B1 = *(const f16x8*)&pwl[(kt * 2 + 1) * 512 + lane * 8];
            f32x4 a = zero4;
            a = __builtin_amdgcn_mfma_f32_16x16x32_f16(A0, B0, a, 0, 0, 0);
            a = __builtin_amdgcn_mfma_f32_16x16x32_f16(A1, B1, a, 0, 0, 0);
            f32x4 lr = lrelu4(a + b1k[kt]);
            if (jt == 6) lr *= m6;  // mask rows j >= 100
            sacc[kt] += lr;
        }
    }

    // agg[k]: C rows are j -> sum 4 in-lane rows then across q groups
    float ag[4];
#pragma unroll
    for (int kt = 0; kt < 4; ++kt) {
        float s = hsum4(sacc[kt]);
        s += __shfl_xor(s, 16);
        s += __shfl_xor(s, 32);
        ag[kt] = s;
    }
    if (lane < 16) {
#pragma unroll
        for (int kt = 0; kt < 4; ++kt) sxin[w][32 + kt * 16 + lane] = ag[kt];
    }

    // node MLP layer 0: lane k, transposed weight row [96]
    {
        const float* wr = tw0n + lane * 96;
        f32x4 acc = zero4;
#pragma unroll
        for (int cc = 0; cc < 24; ++cc) acc += ld4(&sxin[w][cc * 4]) * ld4(wr + cc * 4);
        float s = hsum4(acc) + b0n[lane];
        st0[w][lane] = lrelu(s);
    }
    // node MLP layer 1: lane k<32 x 2 halves, transposed weight row [64]
    {
        int k2 = lane & 31, p = lane >> 5;
        const float* wr = tw1n + k2 * 64 + p * 32;
        f32x4 acc = zero4;
#pragma unroll
        for (int cc = 0; cc < 8; ++cc) acc += ld4(&st0[w][p * 32 + cc * 4]) * ld4(wr + cc * 4);
        float s = hsum4(acc);
        s += __shfl_xor(s, 32);
        if (lane < 32) {
            float hv = lrelu(s + b1n[lane]);
            sh2[w][lane] = hv;
            if (!FINAL) hout[bi * DL + lane] = hv;
        }
    }

    if (FINAL) {
        if (lane < 3) {
            const float* wr = wA + lane * 32;  // OWT row
            f32x4 acc = zero4;
#pragma unroll
            for (int cc = 0; cc < 8; ++cc) acc += ld4(&sh2[w][cc * 4]) * ld4(wr + cc * 4);
            out[bi * 3 + lane] = tanhf(hsum4(acc) + bA[lane]);
        }
    } else {  // U/V for the next step (TUV rows: lane -> U col, 64+lane -> V col)
        const float* tu = wA + lane * 32;
        const float* tv = wA + (64 + lane) * 32;
        f32x4 au = zero4, av = zero4;
#pragma unroll
        for (int cc = 0; cc < 8; ++cc) {
            f32x4 h4 = ld4(&sh2[w][cc * 4]);
            au += h4 * ld4(tu + cc * 4);
            av += h4 * ld4(tv + cc * 4);
        }
        Uo[bi * 64 + lane] = hsum4(au) + bA[lane];
        Vo[bi * 64 + lane] = hsum4(av);
    }
}

extern "C" void kernel_launch(void* const* d_in, const int* in_sizes, int n_in,
                              void* d_out, int out_size, void* d_ws, size_t ws_size,
                              hipStream_t stream) {
    const float* x     = (const float*)d_in[0];
    const float* lin_w = (const float*)d_in[1];
    const float* lin_b = (const float*)d_in[2];
    const float* ew0[2] = {(const float*)d_in[3],  (const float*)d_in[11]};
    const float* eb0[2] = {(const float*)d_in[4],  (const float*)d_in[12]};
    const float* ew1[2] = {(const float*)d_in[5],  (const float*)d_in[13]};
    const float* eb1[2] = {(const float*)d_in[6],  (const float*)d_in[14]};
    const float* nw0[2] = {(const float*)d_in[7],  (const float*)d_in[15]};
    const float* nb0[2] = {(const float*)d_in[8],  (const float*)d_in[16]};
    const float* nw1[2] = {(const float*)d_in[9],  (const float*)d_in[17]};
    const float* nb1[2] = {(const float*)d_in[10], (const float*)d_in[18]};
    const float* ow = (const float*)d_in[19];
    const float* ob = (const float*)d_in[20];
    float* out = (float*)d_out;

    float* h    = (float*)d_ws;         // 6400 x 32
    float* h2   = h + 204800;           // 6400 x 32
    float* U    = h2 + 204800;          // 6400 x 64
    float* V    = U + 409600;           // 6400 x 64
    float* U2   = V + 409600;           // 6400 x 64
    float* V2   = U2 + 409600;          // 6400 x 64
    _Float16* PW = (_Float16*)(V2 + 409600);  // 2 x 4096 f16
    float* TW0n = (float*)(PW + 8192);  // 2 x [64][96]
    float* TW1n = TW0n + 12288;         // 2 x [32][64]
    float* TUV  = TW1n + 4096;          // [128][32]
    float* OWT  = TUV + 4096;           // [3][32]

    k_pre<<<1608, 256, 0, stream>>>(x, lin_w, lin_b, ew0[0], eb0[0], ew1[0], ew1[1],
                                    nw0[0], nw0[1], nw1[0], nw1[1], ew0[1], ow,
                                    h, U, V, PW, TW0n, TW1n, TUV, OWT);
    k_edge<0><<<1600, 256, 0, stream>>>(h, U, V, ew0[0], PW, eb1[0],
                                        TW0n, nb0[0], TW1n, nb1[0],
                                        TUV, eb0[1], h2, U2, V2, nullptr);
    k_edge<1><<<1600, 256, 0, stream>>>(h2, U2, V2, ew0[1], PW + 4096, eb1[1],
                                        TW0n + 6144, nb0[1], TW1n + 2048, nb1[1],
                                        OWT, ob, nullptr, nullptr, nullptr, out);
}

// Round 2
// 203.580 us; speedup vs baseline: 1.1697x; 1.1697x over previous
//
#include <hip/hip_runtime.h>

#define NB 64
#define NN 100
#define DL 32
#define BN (NB * NN)  // 6400

typedef _Float16 f16x8 __attribute__((ext_vector_type(8)));
typedef float f32x4 __attribute__((ext_vector_type(4)));

static __device__ __forceinline__ float lrelu(float x) { return fmaxf(x, 0.1f * x); }
static __device__ __forceinline__ f32x4 lrelu4(f32x4 x) {
    return __builtin_elementwise_max(x, 0.1f * x);
}
static __device__ __forceinline__ f32x4 ld4(const float* p) { return *(const f32x4*)p; }
static __device__ __forceinline__ float hsum4(f32x4 v) { return v[0] + v[1] + v[2] + v[3]; }

// Fused: h = x@lin_w+lin_b, U/V for step 0, and W1 f16 B-fragment prep (both steps).
// Blocks 0..1599: 4 (b,n) rows each. Blocks 1600..1601: PW for step 0/1.
__global__ __launch_bounds__(256) void k_pre(
    const float* __restrict__ x, const float* __restrict__ lw, const float* __restrict__ lb,
    const float* __restrict__ ew0, const float* __restrict__ eb0,
    const float* __restrict__ w1a, const float* __restrict__ w1b,
    float* __restrict__ h, float* __restrict__ U, float* __restrict__ V,
    _Float16* __restrict__ PW) {
    int blk = blockIdx.x;
    int t = threadIdx.x;
    if (blk >= 1600) {  // B-fragment swizzle: PW[step][kt][hf][lane][jj]
        int step = blk - 1600;
        const float* w1 = step ? w1b : w1a;
        _Float16* dst = PW + step * 4096;
#pragma unroll
        for (int u = 0; u < 16; ++u) {
            int idx = t * 16 + u;
            int jj = idx & 7, lane = (idx >> 3) & 63, hf = (idx >> 9) & 1, kt = idx >> 10;
            int c = hf * 32 + (lane >> 4) * 8 + jj;
            int k = kt * 16 + (lane & 15);
            dst[idx] = (_Float16)w1[c * 64 + k];
        }
        return;
    }
    __shared__ float xs[DL];
    __shared__ float hs[4][DL];
    int row0 = blk * 4;
    int b = row0 / NN;  // 4-row group never crosses a batch boundary (100 % 4 == 0)
    if (t < DL) xs[t] = x[b * DL + t];
    __syncthreads();
    if (t < 128) {
        int ni = t >> 5, c = t & 31;
        int n = (row0 + ni) % NN;
        float s = lb[n * DL + c];
#pragma unroll
        for (int cc = 0; cc < DL; ++cc) s += xs[cc] * lw[cc * 3200 + n * DL + c];
        hs[ni][c] = s;
        h[(row0 + ni) * DL + c] = s;
    }
    __syncthreads();
#pragma unroll
    for (int r = 0; r < 2; ++r) {
        int o = r * 256 + t;  // 0..511 : 4 rows x (64 U + 64 V)
        int ni = o >> 7, kw = o & 127;
        int which = kw >> 6, k = kw & 63;
        const float* wp = ew0 + (which ? DL * 64 : 0) + k;
        float s = which ? 0.f : eb0[k];
#pragma unroll
        for (int c = 0; c < DL; ++c) s += hs[ni][c] * wp[c * 64];
        (which ? V : U)[(row0 + ni) * 64 + k] = s;
    }
}

// Per-wave edge+node step: block = 4 waves = 4 (b,i) rows, ONE barrier (PW staging).
// MFMA A-fragments built entirely in registers (lane (q,kk) owns P[row kk][q*8..+7,
// 32+q*8..+7]); wave does all 4 k-tiles itself.  R1 lesson: per-lane weight-ROW
// reads (64 cache lines/instr) destroyed latency hiding -> epilogue + dist are
// wave-cooperative with the ORIGINAL (coalesced) weight layouts.
template <int FINAL>
__global__ __launch_bounds__(256) void k_edge(
    const float* __restrict__ h, const float* __restrict__ U, const float* __restrict__ V,
    const float* __restrict__ w0, const _Float16* __restrict__ PW,
    const float* __restrict__ b1,
    const float* __restrict__ w0n, const float* __restrict__ b0n,
    const float* __restrict__ w1n, const float* __restrict__ b1n,
    const float* __restrict__ wA, const float* __restrict__ bA,
    float* __restrict__ hout, float* __restrict__ Uo, float* __restrict__ Vo,
    float* __restrict__ out) {
    __shared__ __align__(16) _Float16 pwl[4096];
    __shared__ float sdist[4][112];
    __shared__ __align__(16) float sxin[4][96];  // [0..31]=h_i, [32..95]=agg
    __shared__ __align__(16) float st0[4][64];
    __shared__ __align__(16) float sh2[4][32];

    int t = threadIdx.x;
    {  // stage W1 B-fragments once for the whole block
        const f16x8* srcp = (const f16x8*)PW;
        f16x8* dstp = (f16x8*)pwl;
        dstp[t] = srcp[t];
        dstp[t + 256] = srcp[t + 256];
    }
    int w = t >> 6, lane = t & 63, q = lane >> 4, kk = lane & 15;
    int bi = blockIdx.x * 4 + w;
    int b = bi / NN;

    // h_i -> LDS (wave-local; read later via broadcast in the node MLP)
    if (lane < 32) sxin[w][lane] = h[bi * DL + lane];

    // distances: 8 lanes per j (coalesced 32B chunks), shfl-reduce within the group
    {
        int g = lane >> 3, r = lane & 7;
        f32x4 hi4 = ld4(h + bi * DL + r * 4);  // direct global; avoids LDS ordering
        const float* hb = h + b * NN * DL;
#pragma unroll
        for (int it = 0; it < 14; ++it) {
            int j = it * 8 + g;
            int jc = j < NN ? j : NN - 1;
            f32x4 hj4 = ld4(hb + jc * DL + r * 4);
            f32x4 dd = hi4 - hj4;
            float s = dd[0] * dd[0] + dd[1] * dd[1] + dd[2] * dd[2] + dd[3] * dd[3];
            s += __shfl_xor(s, 1);
            s += __shfl_xor(s, 2);
            s += __shfl_xor(s, 4);
            if (r == 0) sdist[w][j] = sqrtf(s + 1e-12f);
        }
    }

    int c0 = q * 8;  // this lane's channel base
    const float* Up = U + (size_t)bi * 64;
    f32x4 u0 = ld4(Up + c0), u1 = ld4(Up + c0 + 4);
    f32x4 u2 = ld4(Up + 32 + c0), u3 = ld4(Up + 36 + c0);
    const float* wd = w0 + 64 * 64;  // dist row of edge W0
    f32x4 d0 = ld4(wd + c0), d1 = ld4(wd + c0 + 4);
    f32x4 d2 = ld4(wd + 32 + c0), d3 = ld4(wd + 36 + c0);
    float b1k[4];
#pragma unroll
    for (int kt = 0; kt < 4; ++kt) b1k[kt] = b1[kt * 16 + kk];
    float m6 = (q == 0) ? 1.f : 0.f;  // tile 6: only rows 96..99 (q==0) are valid

    __syncthreads();  // pwl ready

    f32x4 sacc[4];
    f32x4 zero4 = {0.f, 0.f, 0.f, 0.f};
#pragma unroll
    for (int kt = 0; kt < 4; ++kt) sacc[kt] = zero4;
    const float* Vb = V + (size_t)b * NN * 64;

    // prefetch tile 0 (j = kk < 100, no clamp)
    f32x4 v0, v1, v2, v3;
    float dj;
    {
        const float* vr = Vb + kk * 64 + c0;
        v0 = ld4(vr); v1 = ld4(vr + 4); v2 = ld4(vr + 32); v3 = ld4(vr + 36);
        dj = sdist[w][kk];
    }

#pragma unroll
    for (int jt = 0; jt < 7; ++jt) {
        f32x4 cv0 = v0, cv1 = v1, cv2 = v2, cv3 = v3;
        float cdj = dj;
        if (jt < 6) {  // prefetch next tile's V row + dist (hidden behind MFMAs)
            int j = (jt + 1) * 16 + kk;
            int jc = (jt == 5 && j >= NN) ? NN - 1 : j;
            const float* vr = Vb + jc * 64 + c0;
            v0 = ld4(vr); v1 = ld4(vr + 4); v2 = ld4(vr + 32); v3 = ld4(vr + 36);
            dj = sdist[w][j];
        }
        // P build: exactly this lane's A-fragment elements
        f32x4 p0 = lrelu4(u0 + cv0 + cdj * d0);
        f32x4 p1 = lrelu4(u1 + cv1 + cdj * d1);
        f32x4 p2 = lrelu4(u2 + cv2 + cdj * d2);
        f32x4 p3 = lrelu4(u3 + cv3 + cdj * d3);
        f16x8 A0, A1;
        A0[0] = (_Float16)p0[0]; A0[1] = (_Float16)p0[1];
        A0[2] = (_Float16)p0[2]; A0[3] = (_Float16)p0[3];
        A0[4] = (_Float16)p1[0]; A0[5] = (_Float16)p1[1];
        A0[6] = (_Float16)p1[2]; A0[7] = (_Float16)p1[3];
        A1[0] = (_Float16)p2[0]; A1[1] = (_Float16)p2[1];
        A1[2] = (_Float16)p2[2]; A1[3] = (_Float16)p2[3];
        A1[4] = (_Float16)p3[0]; A1[5] = (_Float16)p3[1];
        A1[6] = (_Float16)p3[2]; A1[7] = (_Float16)p3[3];
#pragma unroll
        for (int kt = 0; kt < 4; ++kt) {
            f16x8 B0 = *(const f16x8*)&pwl[(kt * 2 + 0) * 512 + lane * 8];
            f16x8 B1 = *(const f16x8*)&pwl[(kt * 2 + 1) * 512 + lane * 8];
            f32x4 a = zero4;
            a = __builtin_amdgcn_mfma_f32_16x16x32_f16(A0, B0, a, 0, 0, 0);
            a = __builtin_amdgcn_mfma_f32_16x16x32_f16(A1, B1, a, 0, 0, 0);
            f32x4 lr = lrelu4(a + b1k[kt]);
            if (jt == 6) lr *= m6;  // mask rows j >= 100
            sacc[kt] += lr;
        }
    }

    // agg[k]: sum 4 in-lane C rows then across q groups; col kk -> k = kt*16+kk
    {
        float ag[4];
#pragma unroll
        for (int kt = 0; kt < 4; ++kt) {
            float s = hsum4(sacc[kt]);
            s += __shfl_xor(s, 16);
            s += __shfl_xor(s, 32);
            ag[kt] = s;
        }
        if (lane < 16) {
#pragma unroll
            for (int kt = 0; kt < 4; ++kt) sxin[w][32 + kt * 16 + lane] = ag[kt];
        }
    }

    // node MLP layer 0: lane = output k, ORIGINAL layout w0n[c*64+k] (coalesced,
    // L1-hot); LDS broadcast for inputs; 4 accumulator chains
    {
        float sa = 0.f, sb = 0.f, sc = 0.f, sd = 0.f;
#pragma unroll
        for (int c = 0; c < 96; c += 4) {
            sa += sxin[w][c + 0] * w0n[(c + 0) * 64 + lane];
            sb += sxin[w][c + 1] * w0n[(c + 1) * 64 + lane];
            sc += sxin[w][c + 2] * w0n[(c + 2) * 64 + lane];
            sd += sxin[w][c + 3] * w0n[(c + 3) * 64 + lane];
        }
        st0[w][lane] = lrelu((sa + sb) + (sc + sd) + b0n[lane]);
    }
    // node MLP layer 1: k = lane&31, half p = lane>>5 (16+16 inputs), shfl-combine
    {
        int k2 = lane & 31, p = lane >> 5;
        float sa = 0.f, sb = 0.f;
#pragma unroll
        for (int cc = 0; cc < 32; cc += 2) {
            int c = p * 32 + cc;
            sa += st0[w][c] * w1n[c * DL + k2];
            sb += st0[w][c + 1] * w1n[(c + 1) * DL + k2];
        }
        float s = sa + sb;
        s += __shfl_xor(s, 32);
        if (lane < 32) {
            float hv = lrelu(s + b1n[lane]);
            sh2[w][lane] = hv;
            if (!FINAL) hout[bi * DL + lane] = hv;
        }
    }

    if (FINAL) {
        if (lane < 3) {
            float s = bA[lane];
#pragma unroll
            for (int c = 0; c < DL; ++c) s += sh2[w][c] * wA[c * 3 + lane];
            out[bi * 3 + lane] = tanhf(s);
        }
    } else {  // U/V for the next step, original ew0 layout (coalesced)
        float su = bA[lane], sv = 0.f;
#pragma unroll
        for (int c = 0; c < DL; ++c) {
            float hv = sh2[w][c];
            su += hv * wA[c * 64 + lane];
            sv += hv * wA[(DL + c) * 64 + lane];
        }
        Uo[bi * 64 + lane] = su;
        Vo[bi * 64 + lane] = sv;
    }
}

extern "C" void kernel_launch(void* const* d_in, const int* in_sizes, int n_in,
                              void* d_out, int out_size, void* d_ws, size_t ws_size,
                              hipStream_t stream) {
    const float* x     = (const float*)d_in[0];
    const float* lin_w = (const float*)d_in[1];
    const float* lin_b = (const float*)d_in[2];
    const float* ew0[2] = {(const float*)d_in[3],  (const float*)d_in[11]};
    const float* eb0[2] = {(const float*)d_in[4],  (const float*)d_in[12]};
    const float* ew1[2] = {(const float*)d_in[5],  (const float*)d_in[13]};
    const float* eb1[2] = {(const float*)d_in[6],  (const float*)d_in[14]};
    const float* nw0[2] = {(const float*)d_in[7],  (const float*)d_in[15]};
    const float* nb0[2] = {(const float*)d_in[8],  (const float*)d_in[16]};
    const float* nw1[2] = {(const float*)d_in[9],  (const float*)d_in[17]};
    const float* nb1[2] = {(const float*)d_in[10], (const float*)d_in[18]};
    const float* ow = (const float*)d_in[19];
    const float* ob = (const float*)d_in[20];
    float* out = (float*)d_out;

    float* h    = (float*)d_ws;         // 6400 x 32
    float* h2   = h + 204800;           // 6400 x 32
    float* U    = h2 + 204800;          // 6400 x 64
    float* V    = U + 409600;           // 6400 x 64
    float* U2   = V + 409600;           // 6400 x 64
    float* V2   = U2 + 409600;          // 6400 x 64
    _Float16* PW = (_Float16*)(V2 + 409600);  // 2 x 4096 f16

    k_pre<<<1602, 256, 0, stream>>>(x, lin_w, lin_b, ew0[0], eb0[0], ew1[0], ew1[1],
                                    h, U, V, PW);
    k_edge<0><<<1600, 256, 0, stream>>>(h, U, V, ew0[0], PW, eb1[0],
                                        nw0[0], nb0[0], nw1[0], nb1[0],
                                        ew0[1], eb0[1], h2, U2, V2, nullptr);
    k_edge<1><<<1600, 256, 0, stream>>>(h2, U2, V2, ew0[1], PW + 4096, eb1[1],
                                        nw0[1], nb0[1], nw1[1], nb1[1],
                                        ow, ob, nullptr, nullptr, nullptr, out);
}